// Round 4
// baseline (320.491 us; speedup 1.0000x reference)
//
#include <hip/hip_runtime.h>

#define N_ROWS 32768   // 32 * 32 * 32  (B*H*W)
#define K_CODES 1024
#define CDIM 256

typedef _Float16 half8 __attribute__((ext_vector_type(8)));
typedef _Float16 half4 __attribute__((ext_vector_type(4)));
typedef float floatx16 __attribute__((ext_vector_type(16)));
typedef unsigned long long ull;

// fast-path workspace layout (bytes)
// zh/zl packed q-plane: [32 planes (c/8)][32768 n][8 halves]   (16 MB each)
// cbh/cbl packed q-plane: [32][1024][8]                        (512 KB each)
// part: 32768 x 8 B packed (monotone-val<<32 | code), atomicMin-reduced
#define WS_ZH   0ull
#define WS_ZL   16777216ull
#define WS_CBH  33554432ull
#define WS_CBL  34078720ull
#define WS_CBN  34603008ull
#define WS_PART 34607104ull
#define WS_IDX  36704256ull
#define WS_NEED 36835328ull

__device__ __forceinline__ void g2lds16(const void* g, void* l) {
    __builtin_amdgcn_global_load_lds(
        (const __attribute__((address_space(1))) void*)g,
        (__attribute__((address_space(3))) void*)l, 16, 0, 0);
}

// ============== merged prep: z repack + codebook repack/norms ==============
// blocks [0,2048): z prep (+ part init).  blocks [2048,2304): codebook.
__global__ __launch_bounds__(256) void prep_all(const float* __restrict__ z,
                                                const float* __restrict__ cb,
                                                _Float16* __restrict__ zh,
                                                _Float16* __restrict__ zl,
                                                _Float16* __restrict__ cbh,
                                                _Float16* __restrict__ cbl,
                                                float* __restrict__ cbn,
                                                ull* __restrict__ part) {
    __shared__ float t[64][68];
    if (blockIdx.x >= 2048) {
        int k = ((blockIdx.x - 2048) << 2) | (threadIdx.x >> 6);
        int lane = threadIdx.x & 63;          // c = lane*4
        float4 v = reinterpret_cast<const float4*>(cb + k * CDIM)[lane];
        float s0 = v.x * 32.f, s1 = v.y * 32.f, s2 = v.z * 32.f, s3 = v.w * 32.f;
        half4 hv, lv;
        hv[0] = (_Float16)s0; lv[0] = (_Float16)(s0 - (float)hv[0]);
        hv[1] = (_Float16)s1; lv[1] = (_Float16)(s1 - (float)hv[1]);
        hv[2] = (_Float16)s2; lv[2] = (_Float16)(s2 - (float)hv[2]);
        hv[3] = (_Float16)s3; lv[3] = (_Float16)(s3 - (float)hv[3]);
        // q-plane layout: [c/8][k][8]
        size_t off = (size_t)((lane >> 1) * K_CODES + k) * 8 + ((lane & 1) * 4);
        *reinterpret_cast<half4*>(&cbh[off]) = hv;
        *reinterpret_cast<half4*>(&cbl[off]) = lv;
        float s = s0 * s0 + s1 * s1 + s2 * s2 + s3 * s3;
        #pragma unroll
        for (int off2 = 32; off2 > 0; off2 >>= 1) s += __shfl_down(s, off2);
        if (lane == 0) cbn[k] = s;
        return;
    }
    // part init: 2048 blocks x 16 = 32768 entries
    if (threadIdx.x < 16) part[blockIdx.x * 16 + threadIdx.x] = ~0ull;

    int hwt = blockIdx.x & 15;
    int ct  = (blockIdx.x >> 4) & 3;
    int bb  = blockIdx.x >> 6;
    int tid = threadIdx.x;
    #pragma unroll
    for (int p = 0; p < 4; p++) {
        int e = p * 256 + tid;
        int c = e >> 4, h4 = e & 15;
        float4 v = *reinterpret_cast<const float4*>(
            &z[((bb * 256 + ct * 64 + c) << 10) + hwt * 64 + h4 * 4]);
        *reinterpret_cast<float4*>(&t[c][h4 * 4]) = v;
    }
    __syncthreads();
    #pragma unroll
    for (int p = 0; p < 4; p++) {
        int e = p * 256 + tid;
        int hw = e >> 4, c4 = e & 15;
        half4 hv, lv;
        #pragma unroll
        for (int j = 0; j < 4; j++) {
            float s = t[c4 * 4 + j][hw] * 32.f;
            _Float16 h = (_Float16)s;
            hv[j] = h;
            lv[j] = (_Float16)(s - (float)h);
        }
        int n = bb * 1024 + hwt * 64 + hw;
        int cg = ct * 64 + c4 * 4;
        // q-plane layout: [cg/8][n][8]
        size_t off = (size_t)((cg >> 3) * N_ROWS + n) * 8 + (cg & 7);
        *reinterpret_cast<half4*>(&zh[off]) = hv;
        *reinterpret_cast<half4*>(&zl[off]) = lv;
    }
}

// GEMM+argmin, barrier-free K-loop:
//   block = 256 rows x 64 codes, 4 waves (wave w owns rows w*64..w*64+63).
//   B (64 codes x all 32 k-planes, hi+lo) LDS-resident: staged ONCE.
//   A streamed global->VGPR (coalesced 16B/lane fragment loads).
//   Cross-tile argmin via packed atomicMin (lex (val,code), order-indep).
// d_scaled(n,k) = ||32e||^2 - 2*(32z).(32e) = 1024*d_true (argmin invariant)
__global__ __launch_bounds__(256, 2) void vq_breg(
    const _Float16* __restrict__ zh, const _Float16* __restrict__ zl,
    const _Float16* __restrict__ cbh, const _Float16* __restrict__ cbl,
    const float* __restrict__ cbn, ull* __restrict__ part) {

    __shared__ _Float16 BhL[16384], BlL[16384];   // [plane][code][8], 32 KB ea

    const int tid = threadIdx.x;
    const int lane = tid & 63, w = tid >> 6;
    const int fm = lane & 31, fq = lane >> 5;
    // XCD-chunked bijective swizzle (2048 = 8 XCD * 256): XCD x owns
    // rowTiles [x*16, x*16+16), all 16 codeTiles of a rowTile co-XCD.
    const int L = (blockIdx.x & 7) * 256 + (blockIdx.x >> 3);
    const int codeTile = L & 15;
    const int rowTile  = L >> 4;
    const int rowBase = rowTile * 256, codeBase = codeTile * 64;

    // stage B once: 2048 granules/array; wave reads contiguous 1 KB runs
    #pragma unroll
    for (int p = 0; p < 8; p++) {
        int G = p * 256 + tid;
        int plane = G >> 6, code = G & 63;
        size_t so = ((size_t)plane * K_CODES + codeBase + code) * 8;
        g2lds16(cbh + so, &BhL[G * 8]);
        g2lds16(cbl + so, &BlL[G * 8]);
    }

    float cbnv[2];
    #pragma unroll
    for (int j = 0; j < 2; j++) cbnv[j] = cbn[codeBase + j * 32 + fm];

    floatx16 acc[4];   // [i*2+j]: row-subtile i, code-subtile j
    #pragma unroll
    for (int i = 0; i < 4; i++) acc[i] = (floatx16)0.f;

    __syncthreads();   // B landed (compiler drains vmcnt before barrier)

    const int rw = rowBase + w * 64;
    #pragma unroll
    for (int cc = 0; cc < 8; cc++) {            // 8 chunks of 32 channels
        #pragma unroll
        for (int s = 0; s < 2; s++) {           // two k16 steps per chunk
            const int plane = cc * 4 + s * 2 + fq;
            half8 ah[2], al[2], bh[2], bl[2];
            #pragma unroll
            for (int i = 0; i < 2; i++) {       // A: global->VGPR, coalesced
                size_t ao = ((size_t)plane * N_ROWS + rw + i * 32 + fm) * 8;
                ah[i] = *reinterpret_cast<const half8*>(&zh[ao]);
                al[i] = *reinterpret_cast<const half8*>(&zl[ao]);
            }
            #pragma unroll
            for (int j = 0; j < 2; j++) {       // B: LDS-resident
                int gb = (plane * 64 + j * 32 + fm) * 8;
                bh[j] = *reinterpret_cast<const half8*>(&BhL[gb]);
                bl[j] = *reinterpret_cast<const half8*>(&BlL[gb]);
            }
            #pragma unroll
            for (int i = 0; i < 2; i++)
                #pragma unroll
                for (int j = 0; j < 2; j++) {
                    acc[i*2+j] = __builtin_amdgcn_mfma_f32_32x32x16_f16(ah[i], bh[j], acc[i*2+j], 0, 0, 0);
                    acc[i*2+j] = __builtin_amdgcn_mfma_f32_32x32x16_f16(al[i], bh[j], acc[i*2+j], 0, 0, 0);
                    acc[i*2+j] = __builtin_amdgcn_mfma_f32_32x32x16_f16(ah[i], bl[j], acc[i*2+j], 0, 0, 0);
                }
        }
    }

    // epilogue: d = cbn - 2*acc; per-row argmin over this block's 64 codes,
    // then global packed atomicMin (monotone float map -> lex (val, code)).
    // 32x32 C/D: col = lane&31, row = (reg&3) + 8*(reg>>2) + 4*(lane>>5)
    #pragma unroll
    for (int i = 0; i < 2; i++)
        #pragma unroll
        for (int r = 0; r < 16; r++) {
            float best = 3.4e38f; int bcode = 0x7fffffff;
            #pragma unroll
            for (int j = 0; j < 2; j++) {   // ascending code: strict < = first-min
                float d = fmaf(-2.f, acc[i*2+j][r], cbnv[j]);
                int code = codeBase + j * 32 + fm;
                if (d < best) { best = d; bcode = code; }
            }
            // butterfly over the 32 lanes of this k-half (lex (val, code))
            #pragma unroll
            for (int m = 1; m < 32; m <<= 1) {
                float ov = __shfl_xor(best, m, 64);
                int   oc = __shfl_xor(bcode, m, 64);
                if (ov < best || (ov == best && oc < bcode)) { best = ov; bcode = oc; }
            }
            if (fm == 0) {
                int row = rw + i * 32 + (r & 3) + 8 * (r >> 2) + 4 * fq;
                unsigned u = __float_as_uint(best);
                u = (u & 0x80000000u) ? ~u : (u | 0x80000000u);   // monotone
                atomicMin(&part[row], ((ull)u << 32) | (unsigned)bcode);
            }
        }
}

// finalize + one-hot: 2048 blocks x 16 rows; part already fully reduced.
__global__ __launch_bounds__(256) void onehot_fin3(const ull* __restrict__ part,
                                                   int* __restrict__ idx,
                                                   float* __restrict__ out) {
    __shared__ int sid[16];
    const int rb = blockIdx.x * 16;
    const int tid = threadIdx.x;
    if (tid < 16) {
        int id = (int)(part[rb + tid] & 0xffffffffu);
        sid[tid] = id;
        idx[rb + tid] = id;
    }
    __syncthreads();
    const int k4 = tid << 2;
    #pragma unroll
    for (int r = 0; r < 16; r++) {
        int id = sid[r];
        float4 v4;
        v4.x = (k4     == id) ? 1.f : 0.f;
        v4.y = (k4 + 1 == id) ? 1.f : 0.f;
        v4.z = (k4 + 2 == id) ? 1.f : 0.f;
        v4.w = (k4 + 3 == id) ? 1.f : 0.f;
        reinterpret_cast<float4*>(out)[(size_t)(rb + r) * 256 + tid] = v4;
    }
}

// z_quantized gather, LDS-tiled: 512 blocks, each 256 rows x 64 channels.
__global__ __launch_bounds__(256) void zq_fill2(const int* __restrict__ idx,
                                                const float* __restrict__ cb,
                                                float* __restrict__ out) {
    __shared__ float tile[64][257];     // [c][row]
    const int tid = threadIdx.x;
    const int n0 = (blockIdx.x >> 2) << 8;      // 256-row tile
    const int c0 = (blockIdx.x & 3) << 6;       // 64-channel tile
    const int b  = n0 >> 10;
    const int hw0 = n0 & 1023;

    const int id = idx[n0 + tid];
    const float4* cb4 = reinterpret_cast<const float4*>(cb);
    #pragma unroll
    for (int jj = 0; jj < 16; jj++) {
        float4 v = cb4[id * 64 + (c0 >> 2) + jj];
        tile[jj * 4 + 0][tid] = v.x;
        tile[jj * 4 + 1][tid] = v.y;
        tile[jj * 4 + 2][tid] = v.z;
        tile[jj * 4 + 3][tid] = v.w;
    }
    __syncthreads();
    #pragma unroll
    for (int c = 0; c < 64; c++) {
        out[((size_t)(b * 256 + c0 + c) << 10) + hw0 + tid] = tile[c][tid];
    }
}

// ================= fallback path (round-2 fp32 VALU, known-good) =================

__global__ __launch_bounds__(64) void cb_norms(const float* __restrict__ cb,
                                               float* __restrict__ cbn) {
    int k = blockIdx.x;
    int lane = threadIdx.x;
    float4 v = reinterpret_cast<const float4*>(cb + k * CDIM)[lane];
    float s = v.x * v.x + v.y * v.y + v.z * v.z + v.w * v.w;
    #pragma unroll
    for (int off = 32; off > 0; off >>= 1) s += __shfl_down(s, off);
    if (lane == 0) cbn[k] = s;
}

__global__ __launch_bounds__(256) void cb_transpose(const float* __restrict__ cb,
                                                    float* __restrict__ cbt) {
    __shared__ float t[32][33];
    int k0 = (blockIdx.x & 31) * 32;
    int c0 = (blockIdx.x >> 5) * 32;
    int lane = threadIdx.x & 31;
    int row = threadIdx.x >> 5;
    #pragma unroll
    for (int s = 0; s < 4; s++) {
        int r = row + s * 8;
        t[r][lane] = cb[(k0 + r) * CDIM + c0 + lane];
    }
    __syncthreads();
    #pragma unroll
    for (int s = 0; s < 4; s++) {
        int r = row + s * 8;
        cbt[(c0 + r) * K_CODES + k0 + lane] = t[lane][r];
    }
}

__global__ __launch_bounds__(512, 2) void vq_argmin(const float* __restrict__ z,
                                                    const float* __restrict__ cbt,
                                                    const float* __restrict__ cbn,
                                                    int* __restrict__ idx_out) {
    __shared__ float As[64][128];
    __shared__ float Bs[64][256];

    const int tid = threadIdx.x;
    const int tx = tid & 31;
    const int ty = tid >> 5;
    const int rowBase = blockIdx.x * 128;
    const int bb = rowBase >> 10;
    const int hwBase = rowBase & 1023;

    float minv[8];
    int   mini[8];
    #pragma unroll
    for (int i = 0; i < 8; i++) { minv[i] = 3.4e38f; mini[i] = 0; }

    for (int kt = 0; kt < K_CODES; kt += 256) {
        float acc[2][2][4][4];
        #pragma unroll
        for (int a = 0; a < 2; a++)
            #pragma unroll
            for (int b = 0; b < 2; b++)
                #pragma unroll
                for (int i = 0; i < 4; i++)
                    #pragma unroll
                    for (int j = 0; j < 4; j++) acc[a][b][i][j] = 0.f;

        for (int ccb = 0; ccb < CDIM; ccb += 64) {
            #pragma unroll
            for (int l = 0; l < 4; l++) {
                int f = tid + l * 512;
                int r4 = f & 31, c = f >> 5;
                float4 v = *reinterpret_cast<const float4*>(
                    &z[((bb * 256 + ccb + c) << 10) + hwBase + r4 * 4]);
                *reinterpret_cast<float4*>(&As[c][r4 * 4]) = v;
            }
            #pragma unroll
            for (int l = 0; l < 8; l++) {
                int f = tid + l * 512;
                int k4 = f & 63, c = f >> 6;
                float4 v = *reinterpret_cast<const float4*>(
                    &cbt[(ccb + c) * K_CODES + kt + k4 * 4]);
                *reinterpret_cast<float4*>(&Bs[c][k4 * 4]) = v;
            }
            __syncthreads();
            #pragma unroll 4
            for (int c = 0; c < 64; c++) {
                float4 a0 = *reinterpret_cast<const float4*>(&As[c][ty * 4]);
                float4 a1 = *reinterpret_cast<const float4*>(&As[c][64 + ty * 4]);
                float4 b0 = *reinterpret_cast<const float4*>(&Bs[c][tx * 4]);
                float4 b1 = *reinterpret_cast<const float4*>(&Bs[c][128 + tx * 4]);
                float av[2][4] = {{a0.x, a0.y, a0.z, a0.w}, {a1.x, a1.y, a1.z, a1.w}};
                float bw[2][4] = {{b0.x, b0.y, b0.z, b0.w}, {b1.x, b1.y, b1.z, b1.w}};
                #pragma unroll
                for (int ri = 0; ri < 2; ri++)
                    #pragma unroll
                    for (int i = 0; i < 4; i++)
                        #pragma unroll
                        for (int ci = 0; ci < 2; ci++)
                            #pragma unroll
                            for (int j = 0; j < 4; j++)
                                acc[ri][ci][i][j] =
                                    fmaf(av[ri][i], bw[ci][j], acc[ri][ci][i][j]);
            }
            __syncthreads();
        }
        #pragma unroll
        for (int ci = 0; ci < 2; ci++)
            #pragma unroll
            for (int j = 0; j < 4; j++) {
                int code = kt + ci * 128 + tx * 4 + j;
                float nrm = cbn[code];
                #pragma unroll
                for (int ri = 0; ri < 2; ri++)
                    #pragma unroll
                    for (int i = 0; i < 4; i++) {
                        float d = fmaf(-2.f, acc[ri][ci][i][j], nrm);
                        int r = ri * 4 + i;
                        if (d < minv[r]) { minv[r] = d; mini[r] = code; }
                    }
            }
    }

    __syncthreads();
    float (*rv)[32] = reinterpret_cast<float(*)[32]>(&As[0][0]);
    int   (*rix)[32] = reinterpret_cast<int(*)[32]>(&As[32][0]);
    #pragma unroll
    for (int ri = 0; ri < 2; ri++)
        #pragma unroll
        for (int i = 0; i < 4; i++) {
            int row = ri * 64 + ty * 4 + i;
            rv[row][tx] = minv[ri * 4 + i];
            rix[row][tx] = mini[ri * 4 + i];
        }
    __syncthreads();
    if (tid < 128) {
        float bvv = rv[tid][0]; int bii = rix[tid][0];
        #pragma unroll
        for (int t = 1; t < 32; t++) {
            float v = rv[tid][t]; int ii = rix[tid][t];
            if (v < bvv || (v == bvv && ii < bii)) { bvv = v; bii = ii; }
        }
        idx_out[rowBase + tid] = bii;
    }
}

__global__ __launch_bounds__(256) void onehot_fill(const int* __restrict__ idx,
                                                   float* __restrict__ out) {
    int i = blockIdx.x * 256 + threadIdx.x;
    int n  = i >> 8;
    int k4 = (i & 255) << 2;
    int id = idx[n];
    float4 v;
    v.x = (k4     == id) ? 1.f : 0.f;
    v.y = (k4 + 1 == id) ? 1.f : 0.f;
    v.z = (k4 + 2 == id) ? 1.f : 0.f;
    v.w = (k4 + 3 == id) ? 1.f : 0.f;
    reinterpret_cast<float4*>(out)[i] = v;
}

extern "C" void kernel_launch(void* const* d_in, const int* in_sizes, int n_in,
                              void* d_out, int out_size, void* d_ws, size_t ws_size,
                              hipStream_t stream) {
    const float* z  = (const float*)d_in[0];
    const float* cb = (const float*)d_in[1];
    float* out0 = (float*)d_out;
    float* out1 = out0 + (size_t)N_ROWS * K_CODES;

    if (ws_size >= WS_NEED) {
        _Float16* zh  = (_Float16*)((char*)d_ws + WS_ZH);
        _Float16* zl  = (_Float16*)((char*)d_ws + WS_ZL);
        _Float16* cbh = (_Float16*)((char*)d_ws + WS_CBH);
        _Float16* cbl = (_Float16*)((char*)d_ws + WS_CBL);
        float* cbn = (float*)((char*)d_ws + WS_CBN);
        ull* part = (ull*)((char*)d_ws + WS_PART);
        int* idx = (int*)((char*)d_ws + WS_IDX);

        prep_all<<<2304, 256, 0, stream>>>(z, cb, zh, zl, cbh, cbl, cbn, part);
        vq_breg<<<2048, 256, 0, stream>>>(zh, zl, cbh, cbl, cbn, part);
        onehot_fin3<<<2048, 256, 0, stream>>>(part, idx, out0);
        zq_fill2<<<512, 256, 0, stream>>>(idx, cb, out1);
    } else {
        float* cbn = (float*)d_ws;
        int*   idx = (int*)((char*)d_ws + 4096);
        float* cbt = (float*)((char*)d_ws + 4096 + 131072);

        cb_norms<<<K_CODES, 64, 0, stream>>>(cb, cbn);
        cb_transpose<<<256, 256, 0, stream>>>(cb, cbt);
        vq_argmin<<<N_ROWS / 128, 512, 0, stream>>>(z, cbt, cbn, idx);
        onehot_fill<<<(N_ROWS * K_CODES / 4) / 256, 256, 0, stream>>>(idx, out0);
        zq_fill2<<<512, 256, 0, stream>>>(idx, cb, out1);
    }
}

// Round 5
// 288.810 us; speedup vs baseline: 1.1097x; 1.1097x over previous
//
#include <hip/hip_runtime.h>

#define N_ROWS 32768   // 32 * 32 * 32  (B*H*W)
#define K_CODES 1024
#define CDIM 256

typedef _Float16 half8 __attribute__((ext_vector_type(8)));
typedef _Float16 half4 __attribute__((ext_vector_type(4)));
typedef float floatx16 __attribute__((ext_vector_type(16)));
typedef unsigned long long ull;

// fast-path workspace layout (bytes)
// zh/zl packed q-plane: [32 planes (c/8)][32768 n][8 halves]   (16 MB each)
// cbh/cbl packed q-plane: [32][1024][8]                        (512 KB each)
// part: 32768 x 8 B packed (monotone-val<<32 | code), atomicMin-reduced
#define WS_ZH   0ull
#define WS_ZL   16777216ull
#define WS_CBH  33554432ull
#define WS_CBL  34078720ull
#define WS_CBN  34603008ull
#define WS_PART 34607104ull
#define WS_IDX  36704256ull
#define WS_NEED 36835328ull

__device__ __forceinline__ void g2lds16(const void* g, void* l) {
    __builtin_amdgcn_global_load_lds(
        (const __attribute__((address_space(1))) void*)g,
        (__attribute__((address_space(3))) void*)l, 16, 0, 0);
}

// ============== merged prep: z repack + codebook repack/norms ==============
// blocks [0,2048): z prep (+ part init).  blocks [2048,2304): codebook.
__global__ __launch_bounds__(256) void prep_all(const float* __restrict__ z,
                                                const float* __restrict__ cb,
                                                _Float16* __restrict__ zh,
                                                _Float16* __restrict__ zl,
                                                _Float16* __restrict__ cbh,
                                                _Float16* __restrict__ cbl,
                                                float* __restrict__ cbn,
                                                ull* __restrict__ part) {
    __shared__ float t[64][68];
    if (blockIdx.x >= 2048) {
        int k = ((blockIdx.x - 2048) << 2) | (threadIdx.x >> 6);
        int lane = threadIdx.x & 63;          // c = lane*4
        float4 v = reinterpret_cast<const float4*>(cb + k * CDIM)[lane];
        float s0 = v.x * 32.f, s1 = v.y * 32.f, s2 = v.z * 32.f, s3 = v.w * 32.f;
        half4 hv, lv;
        hv[0] = (_Float16)s0; lv[0] = (_Float16)(s0 - (float)hv[0]);
        hv[1] = (_Float16)s1; lv[1] = (_Float16)(s1 - (float)hv[1]);
        hv[2] = (_Float16)s2; lv[2] = (_Float16)(s2 - (float)hv[2]);
        hv[3] = (_Float16)s3; lv[3] = (_Float16)(s3 - (float)hv[3]);
        // q-plane layout: [c/8][k][8]
        size_t off = (size_t)((lane >> 1) * K_CODES + k) * 8 + ((lane & 1) * 4);
        *reinterpret_cast<half4*>(&cbh[off]) = hv;
        *reinterpret_cast<half4*>(&cbl[off]) = lv;
        float s = s0 * s0 + s1 * s1 + s2 * s2 + s3 * s3;
        #pragma unroll
        for (int off2 = 32; off2 > 0; off2 >>= 1) s += __shfl_down(s, off2);
        if (lane == 0) cbn[k] = s;
        return;
    }
    // part init: 2048 blocks x 16 = 32768 entries
    if (threadIdx.x < 16) part[blockIdx.x * 16 + threadIdx.x] = ~0ull;

    int hwt = blockIdx.x & 15;
    int ct  = (blockIdx.x >> 4) & 3;
    int bb  = blockIdx.x >> 6;
    int tid = threadIdx.x;
    #pragma unroll
    for (int p = 0; p < 4; p++) {
        int e = p * 256 + tid;
        int c = e >> 4, h4 = e & 15;
        float4 v = *reinterpret_cast<const float4*>(
            &z[((bb * 256 + ct * 64 + c) << 10) + hwt * 64 + h4 * 4]);
        *reinterpret_cast<float4*>(&t[c][h4 * 4]) = v;
    }
    __syncthreads();
    #pragma unroll
    for (int p = 0; p < 4; p++) {
        int e = p * 256 + tid;
        int hw = e >> 4, c4 = e & 15;
        half4 hv, lv;
        #pragma unroll
        for (int j = 0; j < 4; j++) {
            float s = t[c4 * 4 + j][hw] * 32.f;
            _Float16 h = (_Float16)s;
            hv[j] = h;
            lv[j] = (_Float16)(s - (float)h);
        }
        int n = bb * 1024 + hwt * 64 + hw;
        int cg = ct * 64 + c4 * 4;
        // q-plane layout: [cg/8][n][8]
        size_t off = (size_t)((cg >> 3) * N_ROWS + n) * 8 + (cg & 7);
        *reinterpret_cast<half4*>(&zh[off]) = hv;
        *reinterpret_cast<half4*>(&zl[off]) = lv;
    }
}

// GEMM+argmin: 128 rows x 128 codes per block, 4 waves (2x2 of 32x32 each),
// K-chunks of 16 channels (one k16 MFMA step), double-buffered 2x16KB LDS,
// T3-minimal schedule: stage(next) BEFORE compute(cur), one __syncthreads
// per chunk (full drain => no ordering fragility). 4 blocks/CU.
// d_scaled(n,k) = ||32e||^2 - 2*(32z).(32e) = 1024*d_true (argmin invariant)
__global__ __launch_bounds__(256, 4) void vq_db(
    const _Float16* __restrict__ zh, const _Float16* __restrict__ zl,
    const _Float16* __restrict__ cbh, const _Float16* __restrict__ cbl,
    const float* __restrict__ cbn, ull* __restrict__ part) {

    // per buffer: [plane(2)][row/code(128)][8 halves] = 4 KB each array
    __shared__ _Float16 AhL[2][2048], AlL[2][2048];
    __shared__ _Float16 BhL[2][2048], BlL[2][2048];   // total 32 KB

    const int tid = threadIdx.x;
    const int lane = tid & 63, wave = tid >> 6;
    const int wm = wave & 1, wn = wave >> 1;   // wave: rows wm*64, codes wn*64
    const int fm = lane & 31, fq = lane >> 5;  // row/col in 32-tile, plane sel
    // XCD-chunked bijective swizzle (2048 = 8 XCD * 256): all 8 codeTiles of
    // a rowTile land on one XCD's L2
    const int L = (blockIdx.x & 7) * 256 + (blockIdx.x >> 3);
    const int codeTile = L & 7;
    const int rowTile  = L >> 3;
    const int rowBase = rowTile * 128, codeBase = codeTile * 128;

    floatx16 acc[4];   // [i*2+j]: row-subtile i, code-subtile j
    #pragma unroll
    for (int i = 0; i < 4; i++) acc[i] = (floatx16)0.f;

    const int p_ = tid >> 7, r_ = tid & 127;   // staged granule: plane, row
    // issue 4 dense global_load_lds (contiguous 1 KB/wave runs) for chunk ch
    auto stage = [&](int buf, int ch) {
        const size_t ao = ((size_t)(ch * 2 + p_) * N_ROWS + rowBase + r_) * 8;
        const size_t bo = ((size_t)(ch * 2 + p_) * K_CODES + codeBase + r_) * 8;
        g2lds16(zh + ao,  &AhL[buf][tid * 8]);
        g2lds16(zl + ao,  &AlL[buf][tid * 8]);
        g2lds16(cbh + bo, &BhL[buf][tid * 8]);
        g2lds16(cbl + bo, &BlL[buf][tid * 8]);
    };
    // one k16 MFMA step on buffer buf (plane = fq within chunk)
    auto compute = [&](int buf) {
        half8 ah[2], al[2], bh[2], bl[2];
        #pragma unroll
        for (int i = 0; i < 2; i++) {
            int ga = fq * 128 + wm * 64 + i * 32 + fm;
            ah[i] = *reinterpret_cast<const half8*>(&AhL[buf][ga * 8]);
            al[i] = *reinterpret_cast<const half8*>(&AlL[buf][ga * 8]);
        }
        #pragma unroll
        for (int j = 0; j < 2; j++) {
            int gb = fq * 128 + wn * 64 + j * 32 + fm;
            bh[j] = *reinterpret_cast<const half8*>(&BhL[buf][gb * 8]);
            bl[j] = *reinterpret_cast<const half8*>(&BlL[buf][gb * 8]);
        }
        #pragma unroll
        for (int i = 0; i < 2; i++)
            #pragma unroll
            for (int j = 0; j < 2; j++) {
                acc[i*2+j] = __builtin_amdgcn_mfma_f32_32x32x16_f16(ah[i], bh[j], acc[i*2+j], 0, 0, 0);
                acc[i*2+j] = __builtin_amdgcn_mfma_f32_32x32x16_f16(al[i], bh[j], acc[i*2+j], 0, 0, 0);
                acc[i*2+j] = __builtin_amdgcn_mfma_f32_32x32x16_f16(ah[i], bl[j], acc[i*2+j], 0, 0, 0);
            }
    };

    stage(0, 0);
    __syncthreads();                            // chunk 0 landed
    for (int c = 0; c < 16; c += 2) {           // static buffer indices
        stage(1, c + 1);                        // overlap: next under compute
        compute(0);
        __syncthreads();                        // c+1 landed; buf0 free
        if (c + 2 < 16) stage(0, c + 2);
        compute(1);
        __syncthreads();                        // c+2 landed; buf1 free
    }

    // epilogue: d = cbn - 2*acc; per-row argmin over this block's 128 codes,
    // then global packed atomicMin (monotone float map -> lex (val, code)).
    // 32x32 C/D: col = lane&31, row = (reg&3) + 8*(reg>>2) + 4*(lane>>5)
    float cbnv[2];
    #pragma unroll
    for (int j = 0; j < 2; j++) cbnv[j] = cbn[codeBase + wn * 64 + j * 32 + fm];

    #pragma unroll
    for (int i = 0; i < 2; i++)
        #pragma unroll
        for (int r = 0; r < 16; r++) {
            float best = 3.4e38f; int bcode = 0x7fffffff;
            #pragma unroll
            for (int j = 0; j < 2; j++) {   // ascending code: strict < = first-min
                float d = fmaf(-2.f, acc[i*2+j][r], cbnv[j]);
                int code = codeBase + wn * 64 + j * 32 + fm;
                if (d < best) { best = d; bcode = code; }
            }
            // butterfly over the 32 lanes of this k-half (lex (val, code))
            #pragma unroll
            for (int m = 1; m < 32; m <<= 1) {
                float ov = __shfl_xor(best, m, 64);
                int   oc = __shfl_xor(bcode, m, 64);
                if (ov < best || (ov == best && oc < bcode)) { best = ov; bcode = oc; }
            }
            if (fm == 0) {
                int row = rowBase + wm * 64 + i * 32 + (r & 3) + 8 * (r >> 2) + 4 * fq;
                unsigned u = __float_as_uint(best);
                u = (u & 0x80000000u) ? ~u : (u | 0x80000000u);   // monotone
                atomicMin(&part[row], ((ull)u << 32) | (unsigned)bcode);
            }
        }
}

// finalize + one-hot: 2048 blocks x 16 rows; part already fully reduced.
__global__ __launch_bounds__(256) void onehot_fin3(const ull* __restrict__ part,
                                                   int* __restrict__ idx,
                                                   float* __restrict__ out) {
    __shared__ int sid[16];
    const int rb = blockIdx.x * 16;
    const int tid = threadIdx.x;
    if (tid < 16) {
        int id = (int)(part[rb + tid] & 0xffffffffu);
        sid[tid] = id;
        idx[rb + tid] = id;
    }
    __syncthreads();
    const int k4 = tid << 2;
    #pragma unroll
    for (int r = 0; r < 16; r++) {
        int id = sid[r];
        float4 v4;
        v4.x = (k4     == id) ? 1.f : 0.f;
        v4.y = (k4 + 1 == id) ? 1.f : 0.f;
        v4.z = (k4 + 2 == id) ? 1.f : 0.f;
        v4.w = (k4 + 3 == id) ? 1.f : 0.f;
        reinterpret_cast<float4*>(out)[(size_t)(rb + r) * 256 + tid] = v4;
    }
}

// z_quantized gather, LDS-tiled: 512 blocks, each 256 rows x 64 channels.
__global__ __launch_bounds__(256) void zq_fill2(const int* __restrict__ idx,
                                                const float* __restrict__ cb,
                                                float* __restrict__ out) {
    __shared__ float tile[64][257];     // [c][row]
    const int tid = threadIdx.x;
    const int n0 = (blockIdx.x >> 2) << 8;      // 256-row tile
    const int c0 = (blockIdx.x & 3) << 6;       // 64-channel tile
    const int b  = n0 >> 10;
    const int hw0 = n0 & 1023;

    const int id = idx[n0 + tid];
    const float4* cb4 = reinterpret_cast<const float4*>(cb);
    #pragma unroll
    for (int jj = 0; jj < 16; jj++) {
        float4 v = cb4[id * 64 + (c0 >> 2) + jj];
        tile[jj * 4 + 0][tid] = v.x;
        tile[jj * 4 + 1][tid] = v.y;
        tile[jj * 4 + 2][tid] = v.z;
        tile[jj * 4 + 3][tid] = v.w;
    }
    __syncthreads();
    #pragma unroll
    for (int c = 0; c < 64; c++) {
        out[((size_t)(b * 256 + c0 + c) << 10) + hw0 + tid] = tile[c][tid];
    }
}

// ================= fallback path (round-2 fp32 VALU, known-good) =================

__global__ __launch_bounds__(64) void cb_norms(const float* __restrict__ cb,
                                               float* __restrict__ cbn) {
    int k = blockIdx.x;
    int lane = threadIdx.x;
    float4 v = reinterpret_cast<const float4*>(cb + k * CDIM)[lane];
    float s = v.x * v.x + v.y * v.y + v.z * v.z + v.w * v.w;
    #pragma unroll
    for (int off = 32; off > 0; off >>= 1) s += __shfl_down(s, off);
    if (lane == 0) cbn[k] = s;
}

__global__ __launch_bounds__(256) void cb_transpose(const float* __restrict__ cb,
                                                    float* __restrict__ cbt) {
    __shared__ float t[32][33];
    int k0 = (blockIdx.x & 31) * 32;
    int c0 = (blockIdx.x >> 5) * 32;
    int lane = threadIdx.x & 31;
    int row = threadIdx.x >> 5;
    #pragma unroll
    for (int s = 0; s < 4; s++) {
        int r = row + s * 8;
        t[r][lane] = cb[(k0 + r) * CDIM + c0 + lane];
    }
    __syncthreads();
    #pragma unroll
    for (int s = 0; s < 4; s++) {
        int r = row + s * 8;
        cbt[(c0 + r) * K_CODES + k0 + lane] = t[lane][r];
    }
}

__global__ __launch_bounds__(512, 2) void vq_argmin(const float* __restrict__ z,
                                                    const float* __restrict__ cbt,
                                                    const float* __restrict__ cbn,
                                                    int* __restrict__ idx_out) {
    __shared__ float As[64][128];
    __shared__ float Bs[64][256];

    const int tid = threadIdx.x;
    const int tx = tid & 31;
    const int ty = tid >> 5;
    const int rowBase = blockIdx.x * 128;
    const int bb = rowBase >> 10;
    const int hwBase = rowBase & 1023;

    float minv[8];
    int   mini[8];
    #pragma unroll
    for (int i = 0; i < 8; i++) { minv[i] = 3.4e38f; mini[i] = 0; }

    for (int kt = 0; kt < K_CODES; kt += 256) {
        float acc[2][2][4][4];
        #pragma unroll
        for (int a = 0; a < 2; a++)
            #pragma unroll
            for (int b = 0; b < 2; b++)
                #pragma unroll
                for (int i = 0; i < 4; i++)
                    #pragma unroll
                    for (int j = 0; j < 4; j++) acc[a][b][i][j] = 0.f;

        for (int ccb = 0; ccb < CDIM; ccb += 64) {
            #pragma unroll
            for (int l = 0; l < 4; l++) {
                int f = tid + l * 512;
                int r4 = f & 31, c = f >> 5;
                float4 v = *reinterpret_cast<const float4*>(
                    &z[((bb * 256 + ccb + c) << 10) + hwBase + r4 * 4]);
                *reinterpret_cast<float4*>(&As[c][r4 * 4]) = v;
            }
            #pragma unroll
            for (int l = 0; l < 8; l++) {
                int f = tid + l * 512;
                int k4 = f & 63, c = f >> 6;
                float4 v = *reinterpret_cast<const float4*>(
                    &cbt[(ccb + c) * K_CODES + kt + k4 * 4]);
                *reinterpret_cast<float4*>(&Bs[c][k4 * 4]) = v;
            }
            __syncthreads();
            #pragma unroll 4
            for (int c = 0; c < 64; c++) {
                float4 a0 = *reinterpret_cast<const float4*>(&As[c][ty * 4]);
                float4 a1 = *reinterpret_cast<const float4*>(&As[c][64 + ty * 4]);
                float4 b0 = *reinterpret_cast<const float4*>(&Bs[c][tx * 4]);
                float4 b1 = *reinterpret_cast<const float4*>(&Bs[c][128 + tx * 4]);
                float av[2][4] = {{a0.x, a0.y, a0.z, a0.w}, {a1.x, a1.y, a1.z, a1.w}};
                float bw[2][4] = {{b0.x, b0.y, b0.z, b0.w}, {b1.x, b1.y, b1.z, b1.w}};
                #pragma unroll
                for (int ri = 0; ri < 2; ri++)
                    #pragma unroll
                    for (int i = 0; i < 4; i++)
                        #pragma unroll
                        for (int ci = 0; ci < 2; ci++)
                            #pragma unroll
                            for (int j = 0; j < 4; j++)
                                acc[ri][ci][i][j] =
                                    fmaf(av[ri][i], bw[ci][j], acc[ri][ci][i][j]);
            }
            __syncthreads();
        }
        #pragma unroll
        for (int ci = 0; ci < 2; ci++)
            #pragma unroll
            for (int j = 0; j < 4; j++) {
                int code = kt + ci * 128 + tx * 4 + j;
                float nrm = cbn[code];
                #pragma unroll
                for (int ri = 0; ri < 2; ri++)
                    #pragma unroll
                    for (int i = 0; i < 4; i++) {
                        float d = fmaf(-2.f, acc[ri][ci][i][j], nrm);
                        int r = ri * 4 + i;
                        if (d < minv[r]) { minv[r] = d; mini[r] = code; }
                    }
            }
    }

    __syncthreads();
    float (*rv)[32] = reinterpret_cast<float(*)[32]>(&As[0][0]);
    int   (*rix)[32] = reinterpret_cast<int(*)[32]>(&As[32][0]);
    #pragma unroll
    for (int ri = 0; ri < 2; ri++)
        #pragma unroll
        for (int i = 0; i < 4; i++) {
            int row = ri * 64 + ty * 4 + i;
            rv[row][tx] = minv[ri * 4 + i];
            rix[row][tx] = mini[ri * 4 + i];
        }
    __syncthreads();
    if (tid < 128) {
        float bvv = rv[tid][0]; int bii = rix[tid][0];
        #pragma unroll
        for (int t = 1; t < 32; t++) {
            float v = rv[tid][t]; int ii = rix[tid][t];
            if (v < bvv || (v == bvv && ii < bii)) { bvv = v; bii = ii; }
        }
        idx_out[rowBase + tid] = bii;
    }
}

__global__ __launch_bounds__(256) void onehot_fill(const int* __restrict__ idx,
                                                   float* __restrict__ out) {
    int i = blockIdx.x * 256 + threadIdx.x;
    int n  = i >> 8;
    int k4 = (i & 255) << 2;
    int id = idx[n];
    float4 v;
    v.x = (k4     == id) ? 1.f : 0.f;
    v.y = (k4 + 1 == id) ? 1.f : 0.f;
    v.z = (k4 + 2 == id) ? 1.f : 0.f;
    v.w = (k4 + 3 == id) ? 1.f : 0.f;
    reinterpret_cast<float4*>(out)[i] = v;
}

extern "C" void kernel_launch(void* const* d_in, const int* in_sizes, int n_in,
                              void* d_out, int out_size, void* d_ws, size_t ws_size,
                              hipStream_t stream) {
    const float* z  = (const float*)d_in[0];
    const float* cb = (const float*)d_in[1];
    float* out0 = (float*)d_out;
    float* out1 = out0 + (size_t)N_ROWS * K_CODES;

    if (ws_size >= WS_NEED) {
        _Float16* zh  = (_Float16*)((char*)d_ws + WS_ZH);
        _Float16* zl  = (_Float16*)((char*)d_ws + WS_ZL);
        _Float16* cbh = (_Float16*)((char*)d_ws + WS_CBH);
        _Float16* cbl = (_Float16*)((char*)d_ws + WS_CBL);
        float* cbn = (float*)((char*)d_ws + WS_CBN);
        ull* part = (ull*)((char*)d_ws + WS_PART);
        int* idx = (int*)((char*)d_ws + WS_IDX);

        prep_all<<<2304, 256, 0, stream>>>(z, cb, zh, zl, cbh, cbl, cbn, part);
        vq_db<<<2048, 256, 0, stream>>>(zh, zl, cbh, cbl, cbn, part);
        onehot_fin3<<<2048, 256, 0, stream>>>(part, idx, out0);
        zq_fill2<<<512, 256, 0, stream>>>(idx, cb, out1);
    } else {
        float* cbn = (float*)d_ws;
        int*   idx = (int*)((char*)d_ws + 4096);
        float* cbt = (float*)((char*)d_ws + 4096 + 131072);

        cb_norms<<<K_CODES, 64, 0, stream>>>(cb, cbn);
        cb_transpose<<<256, 256, 0, stream>>>(cb, cbt);
        vq_argmin<<<N_ROWS / 128, 512, 0, stream>>>(z, cbt, cbn, idx);
        onehot_fill<<<(N_ROWS * K_CODES / 4) / 256, 256, 0, stream>>>(idx, out0);
        zq_fill2<<<512, 256, 0, stream>>>(idx, cb, out1);
    }
}

// Round 7
// 284.105 us; speedup vs baseline: 1.1281x; 1.0166x over previous
//
#include <hip/hip_runtime.h>

#define N_ROWS 32768   // 32 * 32 * 32  (B*H*W)
#define K_CODES 1024
#define CDIM 256

typedef _Float16 half8 __attribute__((ext_vector_type(8)));
typedef _Float16 half4 __attribute__((ext_vector_type(4)));
typedef float floatx16 __attribute__((ext_vector_type(16)));
typedef unsigned long long ull;

// fast-path workspace layout (bytes)
// zh/zl packed q-plane: [32 planes (c/8)][32768 n][8 halves]   (16 MB each)
// cbh/cbl packed q-plane: [32][1024][8]                        (512 KB each)
// part: 32768 x 8 B packed (monotone-val<<32 | code), atomicMin-reduced
#define WS_ZH   0ull
#define WS_ZL   16777216ull
#define WS_CBH  33554432ull
#define WS_CBL  34078720ull
#define WS_CBN  34603008ull
#define WS_PART 34607104ull
#define WS_IDX  36704256ull
#define WS_NEED 36835328ull

__device__ __forceinline__ void g2lds16(const void* g, void* l) {
    __builtin_amdgcn_global_load_lds(
        (const __attribute__((address_space(1))) void*)g,
        (__attribute__((address_space(3))) void*)l, 16, 0, 0);
}

// ============== merged prep: z repack + codebook repack/norms ==============
// blocks [0,2048): z prep (+ part init).  blocks [2048,2304): codebook.
__global__ __launch_bounds__(256) void prep_all(const float* __restrict__ z,
                                                const float* __restrict__ cb,
                                                _Float16* __restrict__ zh,
                                                _Float16* __restrict__ zl,
                                                _Float16* __restrict__ cbh,
                                                _Float16* __restrict__ cbl,
                                                float* __restrict__ cbn,
                                                ull* __restrict__ part) {
    __shared__ float t[64][68];
    if (blockIdx.x >= 2048) {
        int k = ((blockIdx.x - 2048) << 2) | (threadIdx.x >> 6);
        int lane = threadIdx.x & 63;          // c = lane*4
        float4 v = reinterpret_cast<const float4*>(cb + k * CDIM)[lane];
        float s0 = v.x * 32.f, s1 = v.y * 32.f, s2 = v.z * 32.f, s3 = v.w * 32.f;
        half4 hv, lv;
        hv[0] = (_Float16)s0; lv[0] = (_Float16)(s0 - (float)hv[0]);
        hv[1] = (_Float16)s1; lv[1] = (_Float16)(s1 - (float)hv[1]);
        hv[2] = (_Float16)s2; lv[2] = (_Float16)(s2 - (float)hv[2]);
        hv[3] = (_Float16)s3; lv[3] = (_Float16)(s3 - (float)hv[3]);
        // q-plane layout: [c/8][k][8]
        size_t off = (size_t)((lane >> 1) * K_CODES + k) * 8 + ((lane & 1) * 4);
        *reinterpret_cast<half4*>(&cbh[off]) = hv;
        *reinterpret_cast<half4*>(&cbl[off]) = lv;
        float s = s0 * s0 + s1 * s1 + s2 * s2 + s3 * s3;
        #pragma unroll
        for (int off2 = 32; off2 > 0; off2 >>= 1) s += __shfl_down(s, off2);
        if (lane == 0) cbn[k] = s;
        return;
    }
    // part init: 2048 blocks x 16 = 32768 entries
    if (threadIdx.x < 16) part[blockIdx.x * 16 + threadIdx.x] = ~0ull;

    int hwt = blockIdx.x & 15;
    int ct  = (blockIdx.x >> 4) & 3;
    int bb  = blockIdx.x >> 6;
    int tid = threadIdx.x;
    #pragma unroll
    for (int p = 0; p < 4; p++) {
        int e = p * 256 + tid;
        int c = e >> 4, h4 = e & 15;
        float4 v = *reinterpret_cast<const float4*>(
            &z[((bb * 256 + ct * 64 + c) << 10) + hwt * 64 + h4 * 4]);
        *reinterpret_cast<float4*>(&t[c][h4 * 4]) = v;
    }
    __syncthreads();
    #pragma unroll
    for (int p = 0; p < 4; p++) {
        int e = p * 256 + tid;
        int hw = e >> 4, c4 = e & 15;
        half4 hv, lv;
        #pragma unroll
        for (int j = 0; j < 4; j++) {
            float s = t[c4 * 4 + j][hw] * 32.f;
            _Float16 h = (_Float16)s;
            hv[j] = h;
            lv[j] = (_Float16)(s - (float)h);
        }
        int n = bb * 1024 + hwt * 64 + hw;
        int cg = ct * 64 + c4 * 4;
        // q-plane layout: [cg/8][n][8]
        size_t off = (size_t)((cg >> 3) * N_ROWS + n) * 8 + (cg & 7);
        *reinterpret_cast<half4*>(&zh[off]) = hv;
        *reinterpret_cast<half4*>(&zl[off]) = lv;
    }
}

// GEMM+argmin: 128 rows x 128 codes per block, 4 waves (2x2 of 32x32 each),
// K-chunks of 16 channels, double-buffered 2x16KB LDS, COUNTED-vmcnt
// pipeline: raw s_barrier, never vmcnt(0) mid-loop, issue order pinned by
// sched_barrier(0) after every stage group (fixes round-2's failure mode:
// LLVM interleaving independent global_load_lds groups breaks vmcnt math).
// 4 blocks/CU.  d_scaled(n,k) = ||32e||^2 - 2*(32z).(32e) (argmin invariant)
__global__ __launch_bounds__(256, 4) void vq_db(
    const _Float16* __restrict__ zh, const _Float16* __restrict__ zl,
    const _Float16* __restrict__ cbh, const _Float16* __restrict__ cbl,
    const float* __restrict__ cbn, ull* __restrict__ part) {

    // per buffer: [plane(2)][row/code(128)][8 halves] = 4 KB each array
    __shared__ _Float16 AhL[2][2048], AlL[2][2048];
    __shared__ _Float16 BhL[2][2048], BlL[2][2048];   // total 32 KB

    const int tid = threadIdx.x;
    const int lane = tid & 63, wave = tid >> 6;
    const int wm = wave & 1, wn = wave >> 1;   // wave: rows wm*64, codes wn*64
    const int fm = lane & 31, fq = lane >> 5;  // row/col in 32-tile, plane sel
    // XCD-chunked bijective swizzle (2048 = 8 XCD * 256)
    const int L = (blockIdx.x & 7) * 256 + (blockIdx.x >> 3);
    const int codeTile = L & 7;
    const int rowTile  = L >> 3;
    const int rowBase = rowTile * 128, codeBase = codeTile * 128;

    floatx16 acc[4];   // [i*2+j]: row-subtile i, code-subtile j
    #pragma unroll
    for (int i = 0; i < 4; i++) acc[i] = (floatx16)0.f;

    const int p_ = tid >> 7, r_ = tid & 127;   // staged granule: plane, row
    // issue 4 dense global_load_lds for chunk ch; pin issue order after
    auto stage = [&](int buf, int ch) {
        const size_t ao = ((size_t)(ch * 2 + p_) * N_ROWS + rowBase + r_) * 8;
        const size_t bo = ((size_t)(ch * 2 + p_) * K_CODES + codeBase + r_) * 8;
        g2lds16(zh + ao,  &AhL[buf][tid * 8]);
        g2lds16(zl + ao,  &AlL[buf][tid * 8]);
        g2lds16(cbh + bo, &BhL[buf][tid * 8]);
        g2lds16(cbl + bo, &BlL[buf][tid * 8]);
        __builtin_amdgcn_sched_barrier(0);     // group stays in program order
    };
    // one k16 MFMA step on buffer buf (plane = fq within chunk)
    auto compute = [&](int buf) {
        half8 ah[2], al[2], bh[2], bl[2];
        #pragma unroll
        for (int i = 0; i < 2; i++) {
            int ga = fq * 128 + wm * 64 + i * 32 + fm;
            ah[i] = *reinterpret_cast<const half8*>(&AhL[buf][ga * 8]);
            al[i] = *reinterpret_cast<const half8*>(&AlL[buf][ga * 8]);
        }
        #pragma unroll
        for (int j = 0; j < 2; j++) {
            int gb = fq * 128 + wn * 64 + j * 32 + fm;
            bh[j] = *reinterpret_cast<const half8*>(&BhL[buf][gb * 8]);
            bl[j] = *reinterpret_cast<const half8*>(&BlL[buf][gb * 8]);
        }
        #pragma unroll
        for (int i = 0; i < 2; i++)
            #pragma unroll
            for (int j = 0; j < 2; j++) {
                acc[i*2+j] = __builtin_amdgcn_mfma_f32_32x32x16_f16(ah[i], bh[j], acc[i*2+j], 0, 0, 0);
                acc[i*2+j] = __builtin_amdgcn_mfma_f32_32x32x16_f16(al[i], bh[j], acc[i*2+j], 0, 0, 0);
                acc[i*2+j] = __builtin_amdgcn_mfma_f32_32x32x16_f16(ah[i], bl[j], acc[i*2+j], 0, 0, 0);
            }
    };

    stage(0, 0);                                // 4 outstanding
    for (int c = 0; c < 16; c += 2) {           // static buffer indices
        stage(1, c + 1);                        // 8 outstanding
        asm volatile("s_waitcnt vmcnt(4)" ::: "memory");   // chunk c landed
        __builtin_amdgcn_sched_barrier(0);
        __builtin_amdgcn_s_barrier();           // all waves: chunk c ready
        __builtin_amdgcn_sched_barrier(0);
        compute(0);                             // c+1 stays in flight
        __builtin_amdgcn_s_barrier();           // buf0 readers done
        __builtin_amdgcn_sched_barrier(0);
        if (c + 2 < 16) {
            stage(0, c + 2);                    // 8 outstanding
            asm volatile("s_waitcnt vmcnt(4)" ::: "memory");  // c+1 landed
        } else {
            asm volatile("s_waitcnt vmcnt(0)" ::: "memory");  // drain tail
        }
        __builtin_amdgcn_sched_barrier(0);
        __builtin_amdgcn_s_barrier();           // all waves: chunk c+1 ready
        __builtin_amdgcn_sched_barrier(0);
        compute(1);
        __builtin_amdgcn_s_barrier();           // buf1 readers done
        __builtin_amdgcn_sched_barrier(0);
    }

    // epilogue: d = cbn - 2*acc; per-row argmin over this block's 128 codes,
    // then global packed atomicMin (monotone float map -> lex (val, code)).
    // 32x32 C/D: col = lane&31, row = (reg&3) + 8*(reg>>2) + 4*(lane>>5)
    float cbnv[2];
    #pragma unroll
    for (int j = 0; j < 2; j++) cbnv[j] = cbn[codeBase + wn * 64 + j * 32 + fm];

    #pragma unroll
    for (int i = 0; i < 2; i++)
        #pragma unroll
        for (int r = 0; r < 16; r++) {
            float best = 3.4e38f; int bcode = 0x7fffffff;
            #pragma unroll
            for (int j = 0; j < 2; j++) {   // ascending code: strict < = first-min
                float d = fmaf(-2.f, acc[i*2+j][r], cbnv[j]);
                int code = codeBase + wn * 64 + j * 32 + fm;
                if (d < best) { best = d; bcode = code; }
            }
            // butterfly over the 32 lanes of this k-half (lex (val, code))
            #pragma unroll
            for (int m = 1; m < 32; m <<= 1) {
                float ov = __shfl_xor(best, m, 64);
                int   oc = __shfl_xor(bcode, m, 64);
                if (ov < best || (ov == best && oc < bcode)) { best = ov; bcode = oc; }
            }
            if (fm == 0) {
                int row = rowBase + wm * 64 + i * 32 + (r & 3) + 8 * (r >> 2) + 4 * fq;
                unsigned u = __float_as_uint(best);
                u = (u & 0x80000000u) ? ~u : (u | 0x80000000u);   // monotone
                atomicMin(&part[row], ((ull)u << 32) | (unsigned)bcode);
            }
        }
}

// fused finalize: blocks [0,2048) write one-hot (16 rows each); blocks
// [2048,2560) write z_quantized (256 rows x 64 channels each). Both read
// the fully-reduced part[] directly (idx array eliminated).
__global__ __launch_bounds__(256) void finalize(const ull* __restrict__ part,
                                                const float* __restrict__ cb,
                                                float* __restrict__ out0,
                                                float* __restrict__ out1) {
    const int tid = threadIdx.x;
    if (blockIdx.x < 2048) {
        __shared__ int sid[16];
        const int rb = blockIdx.x * 16;
        if (tid < 16) sid[tid] = (int)(part[rb + tid] & 0xffffffffu);
        __syncthreads();
        const int k4 = tid << 2;
        #pragma unroll
        for (int r = 0; r < 16; r++) {
            int id = sid[r];
            float4 v4;
            v4.x = (k4     == id) ? 1.f : 0.f;
            v4.y = (k4 + 1 == id) ? 1.f : 0.f;
            v4.z = (k4 + 2 == id) ? 1.f : 0.f;
            v4.w = (k4 + 3 == id) ? 1.f : 0.f;
            reinterpret_cast<float4*>(out0)[(size_t)(rb + r) * 256 + tid] = v4;
        }
        return;
    }
    // zq phase
    __shared__ float tile[64][257];     // [c][row]
    const int blk = blockIdx.x - 2048;
    const int n0 = (blk >> 2) << 8;             // 256-row tile
    const int c0 = (blk & 3) << 6;              // 64-channel tile
    const int b  = n0 >> 10;
    const int hw0 = n0 & 1023;

    const int id = (int)(part[n0 + tid] & 0xffffffffu);
    const float4* cb4 = reinterpret_cast<const float4*>(cb);
    #pragma unroll
    for (int jj = 0; jj < 16; jj++) {
        float4 v = cb4[id * 64 + (c0 >> 2) + jj];
        tile[jj * 4 + 0][tid] = v.x;
        tile[jj * 4 + 1][tid] = v.y;
        tile[jj * 4 + 2][tid] = v.z;
        tile[jj * 4 + 3][tid] = v.w;
    }
    __syncthreads();
    #pragma unroll
    for (int c = 0; c < 64; c++) {
        out1[((size_t)(b * 256 + c0 + c) << 10) + hw0 + tid] = tile[c][tid];
    }
}

// ================= fallback path (round-2 fp32 VALU, known-good) =================

__global__ __launch_bounds__(64) void cb_norms(const float* __restrict__ cb,
                                               float* __restrict__ cbn) {
    int k = blockIdx.x;
    int lane = threadIdx.x;
    float4 v = reinterpret_cast<const float4*>(cb + k * CDIM)[lane];
    float s = v.x * v.x + v.y * v.y + v.z * v.z + v.w * v.w;
    #pragma unroll
    for (int off = 32; off > 0; off >>= 1) s += __shfl_down(s, off);
    if (lane == 0) cbn[k] = s;
}

__global__ __launch_bounds__(256) void cb_transpose(const float* __restrict__ cb,
                                                    float* __restrict__ cbt) {
    __shared__ float t[32][33];
    int k0 = (blockIdx.x & 31) * 32;
    int c0 = (blockIdx.x >> 5) * 32;
    int lane = threadIdx.x & 31;
    int row = threadIdx.x >> 5;
    #pragma unroll
    for (int s = 0; s < 4; s++) {
        int r = row + s * 8;
        t[r][lane] = cb[(k0 + r) * CDIM + c0 + lane];
    }
    __syncthreads();
    #pragma unroll
    for (int s = 0; s < 4; s++) {
        int r = row + s * 8;
        cbt[(c0 + r) * K_CODES + k0 + lane] = t[lane][r];
    }
}

__global__ __launch_bounds__(512, 2) void vq_argmin(const float* __restrict__ z,
                                                    const float* __restrict__ cbt,
                                                    const float* __restrict__ cbn,
                                                    int* __restrict__ idx_out) {
    __shared__ float As[64][128];
    __shared__ float Bs[64][256];

    const int tid = threadIdx.x;
    const int tx = tid & 31;
    const int ty = tid >> 5;
    const int rowBase = blockIdx.x * 128;
    const int bb = rowBase >> 10;
    const int hwBase = rowBase & 1023;

    float minv[8];
    int   mini[8];
    #pragma unroll
    for (int i = 0; i < 8; i++) { minv[i] = 3.4e38f; mini[i] = 0; }

    for (int kt = 0; kt < K_CODES; kt += 256) {
        float acc[2][2][4][4];
        #pragma unroll
        for (int a = 0; a < 2; a++)
            #pragma unroll
            for (int b = 0; b < 2; b++)
                #pragma unroll
                for (int i = 0; i < 4; i++)
                    #pragma unroll
                    for (int j = 0; j < 4; j++) acc[a][b][i][j] = 0.f;

        for (int ccb = 0; ccb < CDIM; ccb += 64) {
            #pragma unroll
            for (int l = 0; l < 4; l++) {
                int f = tid + l * 512;
                int r4 = f & 31, c = f >> 5;
                float4 v = *reinterpret_cast<const float4*>(
                    &z[((bb * 256 + ccb + c) << 10) + hwBase + r4 * 4]);
                *reinterpret_cast<float4*>(&As[c][r4 * 4]) = v;
            }
            #pragma unroll
            for (int l = 0; l < 8; l++) {
                int f = tid + l * 512;
                int k4 = f & 63, c = f >> 6;
                float4 v = *reinterpret_cast<const float4*>(
                    &cbt[(ccb + c) * K_CODES + kt + k4 * 4]);
                *reinterpret_cast<float4*>(&Bs[c][k4 * 4]) = v;
            }
            __syncthreads();
            #pragma unroll 4
            for (int c = 0; c < 64; c++) {
                float4 a0 = *reinterpret_cast<const float4*>(&As[c][ty * 4]);
                float4 a1 = *reinterpret_cast<const float4*>(&As[c][64 + ty * 4]);
                float4 b0 = *reinterpret_cast<const float4*>(&Bs[c][tx * 4]);
                float4 b1 = *reinterpret_cast<const float4*>(&Bs[c][128 + tx * 4]);
                float av[2][4] = {{a0.x, a0.y, a0.z, a0.w}, {a1.x, a1.y, a1.z, a1.w}};
                float bw[2][4] = {{b0.x, b0.y, b0.z, b0.w}, {b1.x, b1.y, b1.z, b1.w}};
                #pragma unroll
                for (int ri = 0; ri < 2; ri++)
                    #pragma unroll
                    for (int i = 0; i < 4; i++)
                        #pragma unroll
                        for (int ci = 0; ci < 2; ci++)
                            #pragma unroll
                            for (int j = 0; j < 4; j++)
                                acc[ri][ci][i][j] =
                                    fmaf(av[ri][i], bw[ci][j], acc[ri][ci][i][j]);
            }
            __syncthreads();
        }
        #pragma unroll
        for (int ci = 0; ci < 2; ci++)
            #pragma unroll
            for (int j = 0; j < 4; j++) {
                int code = kt + ci * 128 + tx * 4 + j;
                float nrm = cbn[code];
                #pragma unroll
                for (int ri = 0; ri < 2; ri++)
                    #pragma unroll
                    for (int i = 0; i < 4; i++) {
                        float d = fmaf(-2.f, acc[ri][ci][i][j], nrm);
                        int r = ri * 4 + i;
                        if (d < minv[r]) { minv[r] = d; mini[r] = code; }
                    }
            }
    }

    __syncthreads();
    float (*rv)[32] = reinterpret_cast<float(*)[32]>(&As[0][0]);
    int   (*rix)[32] = reinterpret_cast<int(*)[32]>(&As[32][0]);
    #pragma unroll
    for (int ri = 0; ri < 2; ri++)
        #pragma unroll
        for (int i = 0; i < 4; i++) {
            int row = ri * 64 + ty * 4 + i;
            rv[row][tx] = minv[ri * 4 + i];
            rix[row][tx] = mini[ri * 4 + i];
        }
    __syncthreads();
    if (tid < 128) {
        float bvv = rv[tid][0]; int bii = rix[tid][0];
        #pragma unroll
        for (int t = 1; t < 32; t++) {
            float v = rv[tid][t]; int ii = rix[tid][t];
            if (v < bvv || (v == bvv && ii < bii)) { bvv = v; bii = ii; }
        }
        idx_out[rowBase + tid] = bii;
    }
}

__global__ __launch_bounds__(256) void onehot_fill(const int* __restrict__ idx,
                                                   float* __restrict__ out) {
    int i = blockIdx.x * 256 + threadIdx.x;
    int n  = i >> 8;
    int k4 = (i & 255) << 2;
    int id = idx[n];
    float4 v;
    v.x = (k4     == id) ? 1.f : 0.f;
    v.y = (k4 + 1 == id) ? 1.f : 0.f;
    v.z = (k4 + 2 == id) ? 1.f : 0.f;
    v.w = (k4 + 3 == id) ? 1.f : 0.f;
    reinterpret_cast<float4*>(out)[i] = v;
}

__global__ __launch_bounds__(256) void zq_fill2(const int* __restrict__ idx,
                                                const float* __restrict__ cb,
                                                float* __restrict__ out) {
    __shared__ float tile[64][257];     // [c][row]
    const int tid = threadIdx.x;
    const int n0 = (blockIdx.x >> 2) << 8;      // 256-row tile
    const int c0 = (blockIdx.x & 3) << 6;       // 64-channel tile
    const int b  = n0 >> 10;
    const int hw0 = n0 & 1023;

    const int id = idx[n0 + tid];
    const float4* cb4 = reinterpret_cast<const float4*>(cb);
    #pragma unroll
    for (int jj = 0; jj < 16; jj++) {
        float4 v = cb4[id * 64 + (c0 >> 2) + jj];
        tile[jj * 4 + 0][tid] = v.x;
        tile[jj * 4 + 1][tid] = v.y;
        tile[jj * 4 + 2][tid] = v.z;
        tile[jj * 4 + 3][tid] = v.w;
    }
    __syncthreads();
    #pragma unroll
    for (int c = 0; c < 64; c++) {
        out[((size_t)(b * 256 + c0 + c) << 10) + hw0 + tid] = tile[c][tid];
    }
}

extern "C" void kernel_launch(void* const* d_in, const int* in_sizes, int n_in,
                              void* d_out, int out_size, void* d_ws, size_t ws_size,
                              hipStream_t stream) {
    const float* z  = (const float*)d_in[0];
    const float* cb = (const float*)d_in[1];
    float* out0 = (float*)d_out;
    float* out1 = out0 + (size_t)N_ROWS * K_CODES;

    if (ws_size >= WS_NEED) {
        _Float16* zh  = (_Float16*)((char*)d_ws + WS_ZH);
        _Float16* zl  = (_Float16*)((char*)d_ws + WS_ZL);
        _Float16* cbh = (_Float16*)((char*)d_ws + WS_CBH);
        _Float16* cbl = (_Float16*)((char*)d_ws + WS_CBL);
        float* cbn = (float*)((char*)d_ws + WS_CBN);
        ull* part = (ull*)((char*)d_ws + WS_PART);

        prep_all<<<2304, 256, 0, stream>>>(z, cb, zh, zl, cbh, cbl, cbn, part);
        vq_db<<<2048, 256, 0, stream>>>(zh, zl, cbh, cbl, cbn, part);
        finalize<<<2560, 256, 0, stream>>>(part, cb, out0, out1);
    } else {
        float* cbn = (float*)d_ws;
        int*   idx = (int*)((char*)d_ws + 4096);
        float* cbt = (float*)((char*)d_ws + 4096 + 131072);

        cb_norms<<<K_CODES, 64, 0, stream>>>(cb, cbn);
        cb_transpose<<<256, 256, 0, stream>>>(cb, cbt);
        vq_argmin<<<N_ROWS / 128, 512, 0, stream>>>(z, cbt, cbn, idx);
        onehot_fill<<<(N_ROWS * K_CODES / 4) / 256, 256, 0, stream>>>(idx, out0);
        zq_fill2<<<512, 256, 0, stream>>>(idx, cb, out1);
    }
}

// Round 8
// 278.652 us; speedup vs baseline: 1.1501x; 1.0196x over previous
//
#include <hip/hip_runtime.h>

#define N_ROWS 32768   // 32 * 32 * 32  (B*H*W)
#define K_CODES 1024
#define CDIM 256

typedef _Float16 half8 __attribute__((ext_vector_type(8)));
typedef _Float16 half4 __attribute__((ext_vector_type(4)));
typedef float floatx16 __attribute__((ext_vector_type(16)));
typedef unsigned long long ull;

// fast-path workspace layout (bytes)
// zh/zl packed q-plane: [32 planes (c/8)][32768 n][8 halves]   (16 MB each)
// cbh/cbl packed q-plane: [32][1024][8]                        (512 KB each)
// part: 32768 x 8 B packed (monotone-val<<32 | code), atomicMin-reduced
#define WS_ZH   0ull
#define WS_ZL   16777216ull
#define WS_CBH  33554432ull
#define WS_CBL  34078720ull
#define WS_CBN  34603008ull
#define WS_PART 34607104ull
#define WS_IDX  36704256ull
#define WS_NEED 36835328ull

__device__ __forceinline__ void g2lds16(const void* g, void* l) {
    __builtin_amdgcn_global_load_lds(
        (const __attribute__((address_space(1))) void*)g,
        (__attribute__((address_space(3))) void*)l, 16, 0, 0);
}

// ============== merged prep: z repack + codebook repack/norms ==============
// blocks [0,2048): z prep (+ part init).  blocks [2048,2304): codebook.
__global__ __launch_bounds__(256) void prep_all(const float* __restrict__ z,
                                                const float* __restrict__ cb,
                                                _Float16* __restrict__ zh,
                                                _Float16* __restrict__ zl,
                                                _Float16* __restrict__ cbh,
                                                _Float16* __restrict__ cbl,
                                                float* __restrict__ cbn,
                                                ull* __restrict__ part) {
    __shared__ float t[64][68];
    if (blockIdx.x >= 2048) {
        int k = ((blockIdx.x - 2048) << 2) | (threadIdx.x >> 6);
        int lane = threadIdx.x & 63;          // c = lane*4
        float4 v = reinterpret_cast<const float4*>(cb + k * CDIM)[lane];
        float s0 = v.x * 32.f, s1 = v.y * 32.f, s2 = v.z * 32.f, s3 = v.w * 32.f;
        half4 hv, lv;
        hv[0] = (_Float16)s0; lv[0] = (_Float16)(s0 - (float)hv[0]);
        hv[1] = (_Float16)s1; lv[1] = (_Float16)(s1 - (float)hv[1]);
        hv[2] = (_Float16)s2; lv[2] = (_Float16)(s2 - (float)hv[2]);
        hv[3] = (_Float16)s3; lv[3] = (_Float16)(s3 - (float)hv[3]);
        // q-plane layout: [c/8][k][8]
        size_t off = (size_t)((lane >> 1) * K_CODES + k) * 8 + ((lane & 1) * 4);
        *reinterpret_cast<half4*>(&cbh[off]) = hv;
        *reinterpret_cast<half4*>(&cbl[off]) = lv;
        float s = s0 * s0 + s1 * s1 + s2 * s2 + s3 * s3;
        #pragma unroll
        for (int off2 = 32; off2 > 0; off2 >>= 1) s += __shfl_down(s, off2);
        if (lane == 0) cbn[k] = s;
        return;
    }
    // part init: 2048 blocks x 16 = 32768 entries
    if (threadIdx.x < 16) part[blockIdx.x * 16 + threadIdx.x] = ~0ull;

    int hwt = blockIdx.x & 15;
    int ct  = (blockIdx.x >> 4) & 3;
    int bb  = blockIdx.x >> 6;
    int tid = threadIdx.x;
    #pragma unroll
    for (int p = 0; p < 4; p++) {
        int e = p * 256 + tid;
        int c = e >> 4, h4 = e & 15;
        float4 v = *reinterpret_cast<const float4*>(
            &z[((bb * 256 + ct * 64 + c) << 10) + hwt * 64 + h4 * 4]);
        *reinterpret_cast<float4*>(&t[c][h4 * 4]) = v;
    }
    __syncthreads();
    #pragma unroll
    for (int p = 0; p < 4; p++) {
        int e = p * 256 + tid;
        int hw = e >> 4, c4 = e & 15;
        half4 hv, lv;
        #pragma unroll
        for (int j = 0; j < 4; j++) {
            float s = t[c4 * 4 + j][hw] * 32.f;
            _Float16 h = (_Float16)s;
            hv[j] = h;
            lv[j] = (_Float16)(s - (float)h);
        }
        int n = bb * 1024 + hwt * 64 + hw;
        int cg = ct * 64 + c4 * 4;
        // q-plane layout: [cg/8][n][8]
        size_t off = (size_t)((cg >> 3) * N_ROWS + n) * 8 + (cg & 7);
        *reinterpret_cast<half4*>(&zh[off]) = hv;
        *reinterpret_cast<half4*>(&zl[off]) = lv;
    }
}

// GEMM+argmin, A-direct-to-register (r4 structure + the three fixes that
// r4's counters demanded):
//   block = 256 rows x 64 codes, 4 waves (wave w owns rows rw..rw+63).
//   B half-K resident in 32 KB LDS (16 planes), ONE mid-kernel restage.
//   A: global->VGPR with 1-step register prefetch (parity arrays, fully
//   unrolled loop -> static indices). NO in-loop barriers, no counted vmcnt.
//   12 waves/CU (launch_bounds 256,3) of TLP on top of the prefetch.
// d_scaled(n,k) = ||32e||^2 - 2*(32z).(32e) = 1024*d_true (argmin invariant)
__global__ __launch_bounds__(256, 3) void vq_areg(
    const _Float16* __restrict__ zh, const _Float16* __restrict__ zl,
    const _Float16* __restrict__ cbh, const _Float16* __restrict__ cbl,
    const float* __restrict__ cbn, ull* __restrict__ part) {

    __shared__ _Float16 BhL[8192], BlL[8192];   // [plane(16)][code(64)][8], 16 KB ea

    const int tid = threadIdx.x;
    const int lane = tid & 63, w = tid >> 6;
    const int fm = lane & 31, fq = lane >> 5;
    // XCD-chunked bijective swizzle (2048 = 8 XCD * 256): all 16 codeTiles
    // of a rowTile land on one XCD's L2 (A rows served from L2)
    const int L = (blockIdx.x & 7) * 256 + (blockIdx.x >> 3);
    const int codeTile = L & 15;
    const int rowTile  = L >> 4;
    const int rowBase = rowTile * 256, codeBase = codeTile * 64;
    const int rw = rowBase + w * 64;

    // stage B half h (planes h*16 .. h*16+15): 1024 granules per array
    auto stageB = [&](int h) {
        #pragma unroll
        for (int p = 0; p < 4; p++) {
            int G = p * 256 + tid;
            int plane = G >> 6, code = G & 63;
            size_t so = ((size_t)(h * 16 + plane) * K_CODES + codeBase + code) * 8;
            g2lds16(cbh + so, &BhL[G * 8]);
            g2lds16(cbl + so, &BlL[G * 8]);
        }
    };
    // load A fragments for k16 step s (planes 2s, 2s+1 via fq)
    auto loadA = [&](int s, half8 (&h)[2], half8 (&l)[2]) {
        #pragma unroll
        for (int i = 0; i < 2; i++) {
            size_t ao = ((size_t)(2 * s + fq) * N_ROWS + rw + i * 32 + fm) * 8;
            h[i] = *reinterpret_cast<const half8*>(&zh[ao]);
            l[i] = *reinterpret_cast<const half8*>(&zl[ao]);
        }
    };

    float cbnv[2];
    #pragma unroll
    for (int j = 0; j < 2; j++) cbnv[j] = cbn[codeBase + j * 32 + fm];

    floatx16 acc[4];   // [i*2+j]: row-subtile i, code-subtile j
    #pragma unroll
    for (int i = 0; i < 4; i++) acc[i] = (floatx16)0.f;

    half8 pah[2][2], pal[2][2];        // [parity][row-subtile]
    loadA(0, pah[0], pal[0]);
    stageB(0);
    __syncthreads();                   // B half 0 + A step 0 landed

    #pragma unroll
    for (int s = 0; s < 16; s++) {     // 16 k16 steps, fully unrolled
        const int cur = s & 1, nxt = cur ^ 1;
        if (s == 8) {                  // half-K restage (all half-0 reads done)
            __syncthreads();
            stageB(1);
            __syncthreads();
        }
        if (s < 15) loadA(s + 1, pah[nxt], pal[nxt]);   // prefetch next step
        const int lp = (s & 7) * 2 + fq;                // plane in current half
        half8 bh[2], bl[2];
        #pragma unroll
        for (int j = 0; j < 2; j++) {
            int gb = (lp * 64 + j * 32 + fm) * 8;
            bh[j] = *reinterpret_cast<const half8*>(&BhL[gb]);
            bl[j] = *reinterpret_cast<const half8*>(&BlL[gb]);
        }
        #pragma unroll
        for (int i = 0; i < 2; i++)
            #pragma unroll
            for (int j = 0; j < 2; j++) {
                acc[i*2+j] = __builtin_amdgcn_mfma_f32_32x32x16_f16(pah[cur][i], bh[j], acc[i*2+j], 0, 0, 0);
                acc[i*2+j] = __builtin_amdgcn_mfma_f32_32x32x16_f16(pal[cur][i], bh[j], acc[i*2+j], 0, 0, 0);
                acc[i*2+j] = __builtin_amdgcn_mfma_f32_32x32x16_f16(pah[cur][i], bl[j], acc[i*2+j], 0, 0, 0);
            }
    }

    // epilogue (r4-verified): d = cbn - 2*acc; per-row argmin over this
    // block's 64 codes, then packed atomicMin (lex (val, code)).
    // 32x32 C/D: col = lane&31, row = (reg&3) + 8*(reg>>2) + 4*(lane>>5)
    #pragma unroll
    for (int i = 0; i < 2; i++)
        #pragma unroll
        for (int r = 0; r < 16; r++) {
            float best = 3.4e38f; int bcode = 0x7fffffff;
            #pragma unroll
            for (int j = 0; j < 2; j++) {   // ascending code: strict < = first-min
                float d = fmaf(-2.f, acc[i*2+j][r], cbnv[j]);
                int code = codeBase + j * 32 + fm;
                if (d < best) { best = d; bcode = code; }
            }
            // butterfly over the 32 lanes of this k-half (lex (val, code))
            #pragma unroll
            for (int m = 1; m < 32; m <<= 1) {
                float ov = __shfl_xor(best, m, 64);
                int   oc = __shfl_xor(bcode, m, 64);
                if (ov < best || (ov == best && oc < bcode)) { best = ov; bcode = oc; }
            }
            if (fm == 0) {
                int row = rw + i * 32 + (r & 3) + 8 * (r >> 2) + 4 * fq;
                unsigned u = __float_as_uint(best);
                u = (u & 0x80000000u) ? ~u : (u | 0x80000000u);   // monotone
                atomicMin(&part[row], ((ull)u << 32) | (unsigned)bcode);
            }
        }
}

// fused finalize: blocks [0,2048) write one-hot (16 rows each); blocks
// [2048,2560) write z_quantized (256 rows x 64 channels each). Both read
// the fully-reduced part[] directly.
__global__ __launch_bounds__(256) void finalize(const ull* __restrict__ part,
                                                const float* __restrict__ cb,
                                                float* __restrict__ out0,
                                                float* __restrict__ out1) {
    const int tid = threadIdx.x;
    if (blockIdx.x < 2048) {
        __shared__ int sid[16];
        const int rb = blockIdx.x * 16;
        if (tid < 16) sid[tid] = (int)(part[rb + tid] & 0xffffffffu);
        __syncthreads();
        const int k4 = tid << 2;
        #pragma unroll
        for (int r = 0; r < 16; r++) {
            int id = sid[r];
            float4 v4;
            v4.x = (k4     == id) ? 1.f : 0.f;
            v4.y = (k4 + 1 == id) ? 1.f : 0.f;
            v4.z = (k4 + 2 == id) ? 1.f : 0.f;
            v4.w = (k4 + 3 == id) ? 1.f : 0.f;
            reinterpret_cast<float4*>(out0)[(size_t)(rb + r) * 256 + tid] = v4;
        }
        return;
    }
    // zq phase
    __shared__ float tile[64][257];     // [c][row]
    const int blk = blockIdx.x - 2048;
    const int n0 = (blk >> 2) << 8;             // 256-row tile
    const int c0 = (blk & 3) << 6;              // 64-channel tile
    const int b  = n0 >> 10;
    const int hw0 = n0 & 1023;

    const int id = (int)(part[n0 + tid] & 0xffffffffu);
    const float4* cb4 = reinterpret_cast<const float4*>(cb);
    #pragma unroll
    for (int jj = 0; jj < 16; jj++) {
        float4 v = cb4[id * 64 + (c0 >> 2) + jj];
        tile[jj * 4 + 0][tid] = v.x;
        tile[jj * 4 + 1][tid] = v.y;
        tile[jj * 4 + 2][tid] = v.z;
        tile[jj * 4 + 3][tid] = v.w;
    }
    __syncthreads();
    #pragma unroll
    for (int c = 0; c < 64; c++) {
        out1[((size_t)(b * 256 + c0 + c) << 10) + hw0 + tid] = tile[c][tid];
    }
}

// ================= fallback path (round-2 fp32 VALU, known-good) =================

__global__ __launch_bounds__(64) void cb_norms(const float* __restrict__ cb,
                                               float* __restrict__ cbn) {
    int k = blockIdx.x;
    int lane = threadIdx.x;
    float4 v = reinterpret_cast<const float4*>(cb + k * CDIM)[lane];
    float s = v.x * v.x + v.y * v.y + v.z * v.z + v.w * v.w;
    #pragma unroll
    for (int off = 32; off > 0; off >>= 1) s += __shfl_down(s, off);
    if (lane == 0) cbn[k] = s;
}

__global__ __launch_bounds__(256) void cb_transpose(const float* __restrict__ cb,
                                                    float* __restrict__ cbt) {
    __shared__ float t[32][33];
    int k0 = (blockIdx.x & 31) * 32;
    int c0 = (blockIdx.x >> 5) * 32;
    int lane = threadIdx.x & 31;
    int row = threadIdx.x >> 5;
    #pragma unroll
    for (int s = 0; s < 4; s++) {
        int r = row + s * 8;
        t[r][lane] = cb[(k0 + r) * CDIM + c0 + lane];
    }
    __syncthreads();
    #pragma unroll
    for (int s = 0; s < 4; s++) {
        int r = row + s * 8;
        cbt[(c0 + r) * K_CODES + k0 + lane] = t[lane][r];
    }
}

__global__ __launch_bounds__(512, 2) void vq_argmin(const float* __restrict__ z,
                                                    const float* __restrict__ cbt,
                                                    const float* __restrict__ cbn,
                                                    int* __restrict__ idx_out) {
    __shared__ float As[64][128];
    __shared__ float Bs[64][256];

    const int tid = threadIdx.x;
    const int tx = tid & 31;
    const int ty = tid >> 5;
    const int rowBase = blockIdx.x * 128;
    const int bb = rowBase >> 10;
    const int hwBase = rowBase & 1023;

    float minv[8];
    int   mini[8];
    #pragma unroll
    for (int i = 0; i < 8; i++) { minv[i] = 3.4e38f; mini[i] = 0; }

    for (int kt = 0; kt < K_CODES; kt += 256) {
        float acc[2][2][4][4];
        #pragma unroll
        for (int a = 0; a < 2; a++)
            #pragma unroll
            for (int b = 0; b < 2; b++)
                #pragma unroll
                for (int i = 0; i < 4; i++)
                    #pragma unroll
                    for (int j = 0; j < 4; j++) acc[a][b][i][j] = 0.f;

        for (int ccb = 0; ccb < CDIM; ccb += 64) {
            #pragma unroll
            for (int l = 0; l < 4; l++) {
                int f = tid + l * 512;
                int r4 = f & 31, c = f >> 5;
                float4 v = *reinterpret_cast<const float4*>(
                    &z[((bb * 256 + ccb + c) << 10) + hwBase + r4 * 4]);
                *reinterpret_cast<float4*>(&As[c][r4 * 4]) = v;
            }
            #pragma unroll
            for (int l = 0; l < 8; l++) {
                int f = tid + l * 512;
                int k4 = f & 63, c = f >> 6;
                float4 v = *reinterpret_cast<const float4*>(
                    &cbt[(ccb + c) * K_CODES + kt + k4 * 4]);
                *reinterpret_cast<float4*>(&Bs[c][k4 * 4]) = v;
            }
            __syncthreads();
            #pragma unroll 4
            for (int c = 0; c < 64; c++) {
                float4 a0 = *reinterpret_cast<const float4*>(&As[c][ty * 4]);
                float4 a1 = *reinterpret_cast<const float4*>(&As[c][64 + ty * 4]);
                float4 b0 = *reinterpret_cast<const float4*>(&Bs[c][tx * 4]);
                float4 b1 = *reinterpret_cast<const float4*>(&Bs[c][128 + tx * 4]);
                float av[2][4] = {{a0.x, a0.y, a0.z, a0.w}, {a1.x, a1.y, a1.z, a1.w}};
                float bw[2][4] = {{b0.x, b0.y, b0.z, b0.w}, {b1.x, b1.y, b1.z, b1.w}};
                #pragma unroll
                for (int ri = 0; ri < 2; ri++)
                    #pragma unroll
                    for (int i = 0; i < 4; i++)
                        #pragma unroll
                        for (int ci = 0; ci < 2; ci++)
                            #pragma unroll
                            for (int j = 0; j < 4; j++)
                                acc[ri][ci][i][j] =
                                    fmaf(av[ri][i], bw[ci][j], acc[ri][ci][i][j]);
            }
            __syncthreads();
        }
        #pragma unroll
        for (int ci = 0; ci < 2; ci++)
            #pragma unroll
            for (int j = 0; j < 4; j++) {
                int code = kt + ci * 128 + tx * 4 + j;
                float nrm = cbn[code];
                #pragma unroll
                for (int ri = 0; ri < 2; ri++)
                    #pragma unroll
                    for (int i = 0; i < 4; i++) {
                        float d = fmaf(-2.f, acc[ri][ci][i][j], nrm);
                        int r = ri * 4 + i;
                        if (d < minv[r]) { minv[r] = d; mini[r] = code; }
                    }
            }
    }

    __syncthreads();
    float (*rv)[32] = reinterpret_cast<float(*)[32]>(&As[0][0]);
    int   (*rix)[32] = reinterpret_cast<int(*)[32]>(&As[32][0]);
    #pragma unroll
    for (int ri = 0; ri < 2; ri++)
        #pragma unroll
        for (int i = 0; i < 4; i++) {
            int row = ri * 64 + ty * 4 + i;
            rv[row][tx] = minv[ri * 4 + i];
            rix[row][tx] = mini[ri * 4 + i];
        }
    __syncthreads();
    if (tid < 128) {
        float bvv = rv[tid][0]; int bii = rix[tid][0];
        #pragma unroll
        for (int t = 1; t < 32; t++) {
            float v = rv[tid][t]; int ii = rix[tid][t];
            if (v < bvv || (v == bvv && ii < bii)) { bvv = v; bii = ii; }
        }
        idx_out[rowBase + tid] = bii;
    }
}

__global__ __launch_bounds__(256) void onehot_fill(const int* __restrict__ idx,
                                                   float* __restrict__ out) {
    int i = blockIdx.x * 256 + threadIdx.x;
    int n  = i >> 8;
    int k4 = (i & 255) << 2;
    int id = idx[n];
    float4 v;
    v.x = (k4     == id) ? 1.f : 0.f;
    v.y = (k4 + 1 == id) ? 1.f : 0.f;
    v.z = (k4 + 2 == id) ? 1.f : 0.f;
    v.w = (k4 + 3 == id) ? 1.f : 0.f;
    reinterpret_cast<float4*>(out)[i] = v;
}

__global__ __launch_bounds__(256) void zq_fill2(const int* __restrict__ idx,
                                                const float* __restrict__ cb,
                                                float* __restrict__ out) {
    __shared__ float tile[64][257];     // [c][row]
    const int tid = threadIdx.x;
    const int n0 = (blockIdx.x >> 2) << 8;      // 256-row tile
    const int c0 = (blockIdx.x & 3) << 6;       // 64-channel tile
    const int b  = n0 >> 10;
    const int hw0 = n0 & 1023;

    const int id = idx[n0 + tid];
    const float4* cb4 = reinterpret_cast<const float4*>(cb);
    #pragma unroll
    for (int jj = 0; jj < 16; jj++) {
        float4 v = cb4[id * 64 + (c0 >> 2) + jj];
        tile[jj * 4 + 0][tid] = v.x;
        tile[jj * 4 + 1][tid] = v.y;
        tile[jj * 4 + 2][tid] = v.z;
        tile[jj * 4 + 3][tid] = v.w;
    }
    __syncthreads();
    #pragma unroll
    for (int c = 0; c < 64; c++) {
        out[((size_t)(b * 256 + c0 + c) << 10) + hw0 + tid] = tile[c][tid];
    }
}

extern "C" void kernel_launch(void* const* d_in, const int* in_sizes, int n_in,
                              void* d_out, int out_size, void* d_ws, size_t ws_size,
                              hipStream_t stream) {
    const float* z  = (const float*)d_in[0];
    const float* cb = (const float*)d_in[1];
    float* out0 = (float*)d_out;
    float* out1 = out0 + (size_t)N_ROWS * K_CODES;

    if (ws_size >= WS_NEED) {
        _Float16* zh  = (_Float16*)((char*)d_ws + WS_ZH);
        _Float16* zl  = (_Float16*)((char*)d_ws + WS_ZL);
        _Float16* cbh = (_Float16*)((char*)d_ws + WS_CBH);
        _Float16* cbl = (_Float16*)((char*)d_ws + WS_CBL);
        float* cbn = (float*)((char*)d_ws + WS_CBN);
        ull* part = (ull*)((char*)d_ws + WS_PART);

        prep_all<<<2304, 256, 0, stream>>>(z, cb, zh, zl, cbh, cbl, cbn, part);
        vq_areg<<<2048, 256, 0, stream>>>(zh, zl, cbh, cbl, cbn, part);
        finalize<<<2560, 256, 0, stream>>>(part, cb, out0, out1);
    } else {
        float* cbn = (float*)d_ws;
        int*   idx = (int*)((char*)d_ws + 4096);
        float* cbt = (float*)((char*)d_ws + 4096 + 131072);

        cb_norms<<<K_CODES, 64, 0, stream>>>(cb, cbn);
        cb_transpose<<<256, 256, 0, stream>>>(cb, cbt);
        vq_argmin<<<N_ROWS / 128, 512, 0, stream>>>(z, cbt, cbn, idx);
        onehot_fill<<<(N_ROWS * K_CODES / 4) / 256, 256, 0, stream>>>(idx, out0);
        zq_fill2<<<512, 256, 0, stream>>>(idx, cb, out1);
    }
}